// Round 8
// baseline (173.176 us; speedup 1.0000x reference)
//
#include <hip/hip_runtime.h>
#include <hip/hip_fp16.h>
#include <math.h>

#define HH 512
#define WW 512
#define BB 4
#define NCLS 20
#define NINST 32
#define NPIX (HH*WW)
#define NCH 24
#define NBIN 64                 // bins over err in [0,2]; width 1/32
#define NCHUNK3 32
#define CHUNK3 (NPIX/NCHUNK3)   // 8192 pixels
#define LSTR 68                 // u8 row stride per lane (17 words, coprime banks)

// ---- workspace layout (bytes) ----
#define OFF_STATS  ((size_t)0)                       // 8 fields x 128 floats
#define OFF_CLS    (OFF_STATS + 8*128*4)
#define OFF_SEED   (OFF_CLS + 128*4)                 // seedbg[4], seedfg[4]
#define ZERO_BYTES (OFF_SEED + 8*4)
#define OFF_DER    (ZERO_BYTES)                      // 7 x 128 floats
#define OFF_INSTL  (OFF_DER + 7*128*4)
#define OFF_REC    ((OFF_INSTL + 128*4 + 255) & ~(size_t)255)   // uint2[B][NPIX] = 8 MB
#define OFF_HIST   (OFF_REC + (size_t)BB*NPIX*8)     // u32[B][32][NINST][64] = 1 MB

__device__ __forceinline__ float fast_exp(float x) { return __expf(x); }
__device__ __forceinline__ float fast_rcp(float x) { return __builtin_amdgcn_rcpf(x); }
__device__ __forceinline__ float fast_sigmoid(float z) { return fast_rcp(1.0f + __expf(-z)); }
__device__ __forceinline__ float fast_tanh(float x) {
  return 1.0f - 2.0f * fast_rcp(__expf(2.0f * x) + 1.0f);
}

// K1: per-pixel stats, class, seed_bg, and the 8-byte per-pixel record
// {f16 ex, f16 ey, u8 sg_own, u8 (id | valid<<7)} for K3.
__global__ __launch_bounds__(256) void k1_stats(
    const float* __restrict__ pred, const int* __restrict__ inst,
    const int* __restrict__ lab,
    float* __restrict__ stats, int* __restrict__ clsg, float* __restrict__ seedbg,
    uint2* __restrict__ rec)
{
  __shared__ unsigned s_st[4][NINST][9];  // [0]=cnt|G<<16, [1..6]=float bits
  __shared__ int s_cls[NINST];
  __shared__ float s_seed;
  int t = threadIdx.x;
  int w = t >> 6;
  for (int i = t; i < 4*NINST*9; i += 256) ((unsigned*)s_st)[i] = 0u;
  if (t < NINST) s_cls[t] = 0;
  if (t == 0) s_seed = 0.f;
  __syncthreads();

  int b = blockIdx.x >> 8;
  int p = (blockIdx.x & 255) * 1024 + t * 4;   // 4 consecutive pixels
  const float* pb = pred + (size_t)b*NCH*NPIX;
  float4 e0v = *(const float4*)(pb + p);
  float4 e1v = *(const float4*)(pb + NPIX + p);
  float4 g0v = *(const float4*)(pb + 2*NPIX + p);
  float4 g1v = *(const float4*)(pb + 3*NPIX + p);
  int4 idv = *(const int4*)(inst + (size_t)b*NPIX + p);
  int4 lbv = *(const int4*)(lab + (size_t)b*NPIX + p);

  #pragma unroll
  for (int u = 0; u < 4; ++u) {
    int px = p + u;
    int x = px & (WW-1);
    int y = px >> 9;
    float xm = x * (1.0f/(WW-1));
    float ym = y * (1.0f/(HH-1));
    float g0 = (&g0v.x)[u];
    float g1 = (&g1v.x)[u];
    int id = (&idv.x)[u];
    int lb = (&lbv.x)[u];
    if (id >= 1) {
      int j = id - 1;
      unsigned* row = s_st[w][j];
      atomicAdd(&row[0], 1u | ((lb != 255) ? 0x10000u : 0u));
      atomicAdd((float*)&row[1], xm);
      atomicAdd((float*)&row[2], ym);
      atomicAdd((float*)&row[3], g0);
      atomicAdd((float*)&row[4], g1);
      atomicAdd((float*)&row[5], g0*g0);
      atomicAdd((float*)&row[6], g1*g1);
      atomicMax(&s_cls[j], lb);
    }
  }

  float seedloc = 0.f;
  unsigned char so[4] = {0,0,0,0};
  for (int c = 0; c < NCLS; ++c) {
    float4 sv = *(const float4*)(pb + (size_t)(4+c)*NPIX + p);
    #pragma unroll
    for (int u = 0; u < 4; ++u) {
      int lb = (&lbv.x)[u];
      if (lb != 255) {
        float sg = fast_sigmoid((&sv.x)[u]);
        if (c + 1 == lb) so[u] = (unsigned char)(sg*255.f + 0.5f);
        else seedloc += sg*sg;
      }
    }
  }
  // build + store records (32B per thread, coalesced)
  {
    uint2 r4[4];
    #pragma unroll
    for (int u = 0; u < 4; ++u) {
      int px = p + u;
      int x = px & (WW-1);
      int y = px >> 9;
      float ex = fast_tanh((&e0v.x)[u]) + x * (1.0f/(WW-1));
      float ey = fast_tanh((&e1v.x)[u]) + y * (1.0f/(HH-1));
      __half2 h = __floats2half2_rn(ex, ey);
      unsigned lo = *reinterpret_cast<unsigned*>(&h);
      int id = (&idv.x)[u];
      unsigned valid = ((&lbv.x)[u] != 255) ? 1u : 0u;
      unsigned meta = (unsigned)id | (valid << 7);
      r4[u].x = lo;
      r4[u].y = (unsigned)so[u] | (meta << 8);
    }
    uint4* dst = (uint4*)(rec + (size_t)b*NPIX + p);
    dst[0] = make_uint4(r4[0].x, r4[0].y, r4[1].x, r4[1].y);
    dst[1] = make_uint4(r4[2].x, r4[2].y, r4[3].x, r4[3].y);
  }
  for (int o = 32; o; o >>= 1) seedloc += __shfl_down(seedloc, o);
  if ((t & 63) == 0) atomicAdd(&s_seed, seedloc);
  __syncthreads();
  {
    int j = t >> 3, f = t & 7;
    float v;
    if (f == 0) {
      unsigned s = (s_st[0][j][0] & 0xFFFFu) + (s_st[1][j][0] & 0xFFFFu)
                 + (s_st[2][j][0] & 0xFFFFu) + (s_st[3][j][0] & 0xFFFFu);
      v = (float)s;
    } else if (f == 7) {
      unsigned s = (s_st[0][j][0] >> 16) + (s_st[1][j][0] >> 16)
                 + (s_st[2][j][0] >> 16) + (s_st[3][j][0] >> 16);
      v = (float)s;
    } else {
      v = __uint_as_float(s_st[0][j][f]) + __uint_as_float(s_st[1][j][f])
        + __uint_as_float(s_st[2][j][f]) + __uint_as_float(s_st[3][j][f]);
    }
    if (v != 0.f) atomicAdd(&stats[f*128 + b*NINST + j], v);
  }
  if (t < NINST) atomicMax(&clsg[b*NINST + t], s_cls[t]);
  if (t == 0) atomicAdd(&seedbg[b], s_seed);
}

// K2: derive per-pair quantities.
__global__ void k2_derive(const float* __restrict__ stats, const int* __restrict__ clsg,
                          float* __restrict__ der)
{
  int pair = threadIdx.x;
  float cntA = stats[0*128+pair];
  float cnt = fmaxf(cntA, 1.0f);
  float sumx = stats[1*128+pair], sumy = stats[2*128+pair];
  float s0 = stats[3*128+pair], s1 = stats[4*128+pair];
  float q0 = stats[5*128+pair], q1 = stats[6*128+pair];
  float Gv = stats[7*128+pair];
  float cx = sumx/cnt, cy = sumy/cnt;
  float sm0 = s0/cnt, sm1 = s1/cnt;
  float varnum = q0 - 2.f*sm0*s0 + cntA*sm0*sm0
               + q1 - 2.f*sm1*s1 + cntA*sm1*sm1;
  float varl = varnum / (2.0f * cnt);
  int cls = clsg[pair] - 1; if (cls < 0) cls = 0;
  der[0*128+pair] = cx;
  der[1*128+pair] = cy;
  der[2*128+pair] = expf(10.f*sm0);
  der[3*128+pair] = expf(10.f*sm1);
  der[4*128+pair] = varl;
  der[5*128+pair] = Gv;
  der[6*128+pair] = (float)cls;
}

// K3: block = (image, 8192-px chunk, instance-group-of-8). wave = one instance.
// Lane-PRIVATE u8[64] histograms in LDS (stride-68 rows): plain ds_read_u8 /
// ds_write_b8 RMW, zero atomics in the hot loop. Positives via rare atomics.
__global__ __launch_bounds__(512) void k3_hist(
    const uint2* __restrict__ rec, const float* __restrict__ der,
    unsigned* __restrict__ hist, float* __restrict__ seedfg)
{
  __shared__ unsigned char lhist[8*64*LSTR];   // 34,816 B, lane-private rows
  __shared__ unsigned hc_pos[8*NBIN];          // 2 KB, shared (rare atomics)
  int t = threadIdx.x;
  for (int i = t; i < 8*64*LSTR/4; i += 512) ((unsigned*)lhist)[i] = 0u;
  for (int i = t; i < 8*NBIN; i += 512) hc_pos[i] = 0u;
  __syncthreads();

  int bid = blockIdx.x;                   // B * 32 * 4 = 512
  int b = bid >> 7;
  int chunk = (bid >> 2) & 31;
  int ig = bid & 3;
  int w = t >> 6;
  int lane = t & 63;
  int j = ig*8 + w;                       // this wave's instance
  int pair = b*NINST + j;
  float cx = der[0*128+pair], cy = der[1*128+pair];
  float s0 = der[2*128+pair], s1 = der[3*128+pair];
  const uint2* rb = rec + (size_t)b*NPIX + chunk*CHUNK3;
  unsigned char* hrow = lhist + (w*64 + lane)*LSTR;
  unsigned* posrow = hc_pos + w*NBIN;
  float fg = 0.f;
  int jp1 = j + 1;

  #pragma unroll 4
  for (int it = 0; it < CHUNK3/64; ++it) {
    uint2 r = rb[it*64 + lane];
    __half2 h;
    *reinterpret_cast<unsigned*>(&h) = r.x;
    float2 e = __half22float2(h);
    unsigned hi = r.y;
    int id = (int)((hi >> 8) & 0x3F);
    float dx = e.x - cx, dy = e.y - cy;
    float dist = fast_exp(-(dx*dx*s0 + dy*dy*s1));
    bool own = (id == jp1);
    if (own) {
      float sg = (float)(hi & 0xFFu) * (1.0f/255.f);
      float d = sg - dist;
      fg += d*d;
    }
    if (hi & 0x8000u) {                    // valid
      float f = own ? (1.0f - dist) : dist;          // err/2 in [0,1]
      unsigned bin = min((unsigned)(f * (float)NBIN), NBIN-1u);
      hrow[bin] = (unsigned char)(hrow[bin] + 1);    // lane-private RMW
      if (own) atomicAdd(&posrow[bin], 1u);          // rare
    }
  }

  for (int o = 32; o; o >>= 1) fg += __shfl_down(fg, o);
  if (lane == 0) atomicAdd(&seedfg[b], 10.0f * fg);  // fg_w = 10

  __syncthreads();
  // flush: lane = bin; sum this wave's 64 lane-rows at this bin.
  {
    unsigned cnt = 0;
    const unsigned char* basep = lhist + (w*64)*LSTR + lane;
    #pragma unroll 8
    for (int src = 0; src < 64; ++src) cnt += basep[src*LSTR];
    unsigned pos = posrow[lane];
    hist[(((size_t)b*NCHUNK3 + chunk)*NINST + j)*NBIN + lane] = cnt | (pos << 16);
  }
}

// K4: per pair: sum 32 chunk-histograms (64 bins), descending Lovasz scan.
__global__ __launch_bounds__(64) void k4_scan(
    const unsigned* __restrict__ hist, const float* __restrict__ der,
    float* __restrict__ instl)
{
  int pair = blockIdx.x;
  int lane = threadIdx.x;                 // 0..63
  int b = pair >> 5, j = pair & 31;
  unsigned c = 0, p = 0;
  #pragma unroll 8
  for (int ch = 0; ch < NCHUNK3; ++ch) {
    unsigned v = hist[(((size_t)b*NCHUNK3 + ch)*NINST + j)*NBIN + lane];
    c += v & 0xFFFFu; p += v >> 16;
  }
  // descending over bins: lane 0 -> bin 63
  int k = NBIN - 1 - lane;
  unsigned n = __shfl(c, 63 - k);         // value at bin k (our own c is bin=lane)
  unsigned pp0 = __shfl(p, 63 - k);
  // n,pp0 now ordered descending by lane
  for (int off = 1; off < 64; off <<= 1) {
    unsigned nn = __shfl_up(n, off);
    unsigned pq = __shfl_up(pp0, off);
    if (lane >= off) { n += nn; pp0 += pq; }
  }
  float G = der[5*128+pair];
  float fN = (float)n;
  float fP = (float)pp0;
  float uni = G + fN - fP;
  float J = 1.0f - (G - fP) / fmaxf(uni, 1e-9f);
  float Jp = __shfl_up(J, 1);
  if (lane == 0) Jp = 0.f;
  float v = (k + 0.5f) * (2.0f/NBIN);
  float L = v * (J - Jp);
  for (int o = 32; o; o >>= 1) L += __shfl_down(L, o);
  if (lane == 0) instl[pair] = L;
}

// K5: final combine.
__global__ void k5_final(const float* __restrict__ instl, const float* __restrict__ der,
                         const float* __restrict__ seedbg, const float* __restrict__ seedfg,
                         float* __restrict__ out)
{
  __shared__ float red[128];
  int t = threadIdx.x;
  float v = instl[t]*(1.0f/NINST) + 10.0f*der[4*128+t]*(1.0f/NINST);
  red[t] = v; __syncthreads();
  for (int s = 64; s; s >>= 1) { if (t < s) red[t] += red[t+s]; __syncthreads(); }
  if (t == 0) {
    float tot = red[0];
    for (int b = 0; b < BB; ++b) tot += (seedbg[b] + seedfg[b]) * (1.0f/NPIX);
    out[0] = tot * (1.0f/BB);
  }
}

extern "C" void kernel_launch(void* const* d_in, const int* in_sizes, int n_in,
                              void* d_out, int out_size, void* d_ws, size_t ws_size,
                              hipStream_t stream)
{
  const float* pred = (const float*)d_in[0];
  const int* inst = (const int*)d_in[1];
  const int* lab  = (const int*)d_in[2];
  char* ws = (char*)d_ws;
  float* stats = (float*)(ws + OFF_STATS);
  int* clsg = (int*)(ws + OFF_CLS);
  float* seedbg = (float*)(ws + OFF_SEED);
  float* seedfg = seedbg + 4;
  float* der = (float*)(ws + OFF_DER);
  float* instl = (float*)(ws + OFF_INSTL);
  uint2* rec = (uint2*)(ws + OFF_REC);
  unsigned* hist = (unsigned*)(ws + OFF_HIST);

  hipMemsetAsync(ws, 0, ZERO_BYTES, stream);
  hipLaunchKernelGGL(k1_stats, dim3(BB*256), dim3(256), 0, stream,
                     pred, inst, lab, stats, clsg, seedbg, rec);
  hipLaunchKernelGGL(k2_derive, dim3(1), dim3(128), 0, stream, stats, clsg, der);
  hipLaunchKernelGGL(k3_hist, dim3(BB*NCHUNK3*4), dim3(512), 0, stream,
                     rec, der, hist, seedfg);
  hipLaunchKernelGGL(k4_scan, dim3(128), dim3(64), 0, stream, hist, der, instl);
  hipLaunchKernelGGL(k5_final, dim3(1), dim3(128), 0, stream, instl, der, seedbg, seedfg, (float*)d_out);
}

// Round 9
// 91.688 us; speedup vs baseline: 1.8888x; 1.8888x over previous
//
#include <hip/hip_runtime.h>
#include <hip/hip_fp16.h>
#include <math.h>

#define HH 512
#define WW 512
#define BB 4
#define NCLS 20
#define NINST 32
#define NPIX (HH*WW)
#define NCH 24
#define NBIN 128                // bins over err/2 in [0,1]; err bin width 1/64
#define NCHUNK3 256
#define CPX3 1024               // pixels per K3 block
#define K3T 512
#define HSTR 33                 // hc row stride (u32): bank(bin*33+j)%32=(bin+j)%32

// ---- workspace layout (bytes) ----
#define OFF_PARTA  ((size_t)0)                       // float[256 blocks][8f*32j]
#define OFF_PSEED  (OFF_PARTA + 256*256*4)           // float[256]
#define OFF_DER    (OFF_PSEED + 256*4)               // float[7][128]
#define OFF_SEEDBG (OFF_DER + 7*128*4)               // float[4]
#define OFF_INSTL  (OFF_SEEDBG + 4*4)                // float[128]
#define OFF_SFG    (OFF_INSTL + 128*4)               // float[1024]
#define OFF_REC    ((OFF_SFG + 1024*4 + 255) & ~(size_t)255)  // uint2[B][NPIX] = 8MB
#define OFF_HIST   (OFF_REC + (size_t)BB*NPIX*8)     // u32[B][256][32][128] = 16MB

__device__ __forceinline__ float fast_rcp(float x) { return __builtin_amdgcn_rcpf(x); }
__device__ __forceinline__ float fast_sigmoid(float z) { return fast_rcp(1.0f + __expf(-z)); }
__device__ __forceinline__ float fast_tanh(float x) {
  return 1.0f - 2.0f * fast_rcp(__expf(2.0f * x) + 1.0f);
}

// K1: 256 blocks (64/image), 16 px/thread. Per-pixel stats to per-block
// partials (NO global atomics), seed_bg partial, 8-byte rec for K3.
__global__ __launch_bounds__(256) void k1_stats(
    const float* __restrict__ pred, const int* __restrict__ inst,
    const int* __restrict__ lab,
    float* __restrict__ partA, float* __restrict__ partSeed,
    uint2* __restrict__ rec)
{
  __shared__ unsigned s_st[4][NINST][9];  // [0]=cnt|G<<16, [1..6]=float bits
  __shared__ float s_seed;
  int t = threadIdx.x;
  int w = t >> 6;
  for (int i = t; i < 4*NINST*9; i += 256) ((unsigned*)s_st)[i] = 0u;
  if (t == 0) s_seed = 0.f;
  __syncthreads();

  int b = blockIdx.x >> 6;
  int blk = blockIdx.x & 63;
  const float* pb = pred + (size_t)b*NCH*NPIX;
  float seedloc = 0.f;

  for (int r = 0; r < 4; ++r) {
    int p = blk*4096 + r*1024 + t*4;
    float4 e0v = *(const float4*)(pb + p);
    float4 e1v = *(const float4*)(pb + NPIX + p);
    float4 g0v = *(const float4*)(pb + 2*NPIX + p);
    float4 g1v = *(const float4*)(pb + 3*NPIX + p);
    int4 idv = *(const int4*)(inst + (size_t)b*NPIX + p);
    int4 lbv = *(const int4*)(lab + (size_t)b*NPIX + p);

    #pragma unroll
    for (int u = 0; u < 4; ++u) {
      int px = p + u;
      int x = px & (WW-1);
      int y = px >> 9;
      float xm = x * (1.0f/(WW-1));
      float ym = y * (1.0f/(HH-1));
      float g0 = (&g0v.x)[u];
      float g1 = (&g1v.x)[u];
      int id = (&idv.x)[u];
      int lb = (&lbv.x)[u];
      if (id >= 1) {
        int j = id - 1;
        unsigned* row = s_st[w][j];
        atomicAdd(&row[0], 1u | ((lb != 255) ? 0x10000u : 0u));
        atomicAdd((float*)&row[1], xm);
        atomicAdd((float*)&row[2], ym);
        atomicAdd((float*)&row[3], g0);
        atomicAdd((float*)&row[4], g1);
        atomicAdd((float*)&row[5], g0*g0);
        atomicAdd((float*)&row[6], g1*g1);
      }
    }

    float so[4] = {0.f,0.f,0.f,0.f};
    float Sv[4] = {0.f,0.f,0.f,0.f};
    for (int c = 0; c < NCLS; ++c) {
      float4 sv = *(const float4*)(pb + (size_t)(4+c)*NPIX + p);
      #pragma unroll
      for (int u = 0; u < 4; ++u) {
        float sg = fast_sigmoid((&sv.x)[u]);
        Sv[u] += sg*sg;
        if (c + 1 == (&lbv.x)[u]) so[u] = sg;
      }
    }
    #pragma unroll
    for (int u = 0; u < 4; ++u)
      if ((&lbv.x)[u] != 255) seedloc += Sv[u] - so[u]*so[u];

    // rec: {f16 ex, f16 ey, u8 sg_own, u8 (id | valid<<7)}
    uint2 r4[4];
    #pragma unroll
    for (int u = 0; u < 4; ++u) {
      int px = p + u;
      int x = px & (WW-1);
      int y = px >> 9;
      float ex = fast_tanh((&e0v.x)[u]) + x * (1.0f/(WW-1));
      float ey = fast_tanh((&e1v.x)[u]) + y * (1.0f/(HH-1));
      __half2 h = __floats2half2_rn(ex, ey);
      unsigned valid = ((&lbv.x)[u] != 255) ? 1u : 0u;
      unsigned meta = (unsigned)(&idv.x)[u] | (valid << 7);
      r4[u].x = *reinterpret_cast<unsigned*>(&h);
      r4[u].y = (unsigned)(unsigned char)(so[u]*255.f + 0.5f) | (meta << 8);
    }
    uint4* dst = (uint4*)(rec + (size_t)b*NPIX + p);
    dst[0] = make_uint4(r4[0].x, r4[0].y, r4[1].x, r4[1].y);
    dst[1] = make_uint4(r4[2].x, r4[2].y, r4[3].x, r4[3].y);
  }

  for (int o = 32; o; o >>= 1) seedloc += __shfl_down(seedloc, o);
  if ((t & 63) == 0) atomicAdd(&s_seed, seedloc);
  __syncthreads();

  if (t < 256) {
    int j = t & 31, f = t >> 5;
    float v;
    if (f == 0) {
      unsigned s = (s_st[0][j][0] & 0xFFFFu) + (s_st[1][j][0] & 0xFFFFu)
                 + (s_st[2][j][0] & 0xFFFFu) + (s_st[3][j][0] & 0xFFFFu);
      v = (float)s;
    } else if (f == 7) {
      unsigned s = (s_st[0][j][0] >> 16) + (s_st[1][j][0] >> 16)
                 + (s_st[2][j][0] >> 16) + (s_st[3][j][0] >> 16);
      v = (float)s;
    } else {
      v = __uint_as_float(s_st[0][j][f]) + __uint_as_float(s_st[1][j][f])
        + __uint_as_float(s_st[2][j][f]) + __uint_as_float(s_st[3][j][f]);
    }
    partA[(blockIdx.x << 8) + t] = v;
  }
  if (t == 0) partSeed[blockIdx.x] = s_seed;
}

// K2: reduce partials + derive per-pair constants. One block, 1024 threads.
__global__ __launch_bounds__(1024) void k2_reduce(
    const float* __restrict__ partA, const float* __restrict__ partSeed,
    float* __restrict__ der, float* __restrict__ seedbg)
{
  __shared__ float s_stats[8][128];
  int t = threadIdx.x;
  {
    int f = t >> 7, pair = t & 127;
    int b = pair >> 5, j = pair & 31;
    float s = 0.f;
    for (int blk = 0; blk < 64; ++blk)
      s += partA[((b*64 + blk) << 8) + (f << 5) + j];
    s_stats[f][pair] = s;
  }
  if (t < 4) {
    float ss = 0.f;
    for (int i = 0; i < 64; ++i) ss += partSeed[t*64 + i];
    seedbg[t] = ss;
  }
  __syncthreads();
  if (t < 128) {
    float cntA = s_stats[0][t];
    float cnt = fmaxf(cntA, 1.0f);
    float sumx = s_stats[1][t], sumy = s_stats[2][t];
    float s0 = s_stats[3][t], s1 = s_stats[4][t];
    float q0 = s_stats[5][t], q1 = s_stats[6][t];
    float Gv = s_stats[7][t];
    float cx = sumx/cnt, cy = sumy/cnt;
    float sm0 = s0/cnt, sm1 = s1/cnt;
    float varnum = q0 - 2.f*sm0*s0 + cntA*sm0*sm0
                 + q1 - 2.f*sm1*s1 + cntA*sm1*sm1;
    float varl = varnum / (2.0f * cnt);
    der[0*128+t] = cx;
    der[1*128+t] = cy;
    der[2*128+t] = -1.442695041f * expf(10.f*sm0);  // pre-scaled for exp2
    der[3*128+t] = -1.442695041f * expf(10.f*sm1);
    der[4*128+t] = varl;
    der[5*128+t] = Gv;
  }
}

// K3: block = (image, 1024-px chunk); 8 waves; lane = (px-slot<<5)|instance.
// hc[bin*33 + inst] -> atomic bank = (bin+inst)%32: 32 distinct banks per
// half-wave, 2/bank per wave (free). No staging; rec via L1 broadcast.
__global__ __launch_bounds__(K3T) void k3_hist(
    const uint2* __restrict__ rec, const float* __restrict__ der,
    unsigned* __restrict__ hist, float* __restrict__ sfg)
{
  __shared__ unsigned hc[NBIN*HSTR];      // 16.9 KB
  __shared__ float s_fg[8];
  int t = threadIdx.x;
  for (int i = t; i < NBIN*HSTR; i += K3T) hc[i] = 0u;
  int bid = blockIdx.x;                   // 1024
  int b = bid >> 8;
  int chunk = bid & 255;
  int w = t >> 6, lane = t & 63;
  int j = lane & 31, jp1 = j + 1;
  int pair = b*NINST + j;
  float cx = der[0*128+pair], cy = der[1*128+pair];
  float s0 = der[2*128+pair], s1 = der[3*128+pair];   // = -1.4427*exp(10 sm)
  const uint2* rb = rec + (size_t)b*NPIX + chunk*CPX3 + w*128;
  __syncthreads();

  float fg = 0.f;
  #pragma unroll 4
  for (int r = 0; r < 64; ++r) {
    uint2 rv = rb[r*2 + (lane >> 5)];
    __half2 h;
    *reinterpret_cast<unsigned*>(&h) = rv.x;
    float2 e = __half22float2(h);
    unsigned hi = rv.y;
    float dx = e.x - cx, dy = e.y - cy;
    float dist = exp2f(dx*dx*s0 + dy*dy*s1);
    bool own = ((int)((hi >> 8) & 0x3F) == jp1);
    if (own) { float d = (float)(hi & 0xFFu)*(1.0f/255.f) - dist; fg += d*d; }
    if (hi & 0x8000u) {
      float f = own ? (1.0f - dist) : dist;            // err/2 in [0,1]
      unsigned bin = min((unsigned)(f * (float)NBIN), NBIN-1u);
      atomicAdd(&hc[bin*HSTR + j], own ? 0x10001u : 1u);
    }
  }
  for (int o = 32; o; o >>= 1) fg += __shfl_down(fg, o);
  if (lane == 0) s_fg[w] = fg;
  __syncthreads();
  if (t == 0) {
    float s = 0.f;
    #pragma unroll
    for (int i = 0; i < 8; ++i) s += s_fg[i];
    sfg[bid] = 10.0f * s;                  // fg_w = 10
  }
  // transposed flush -> hist[b][chunk][inst][bin] (coalesced for K4)
  unsigned* out = hist + (size_t)(b*NCHUNK3 + chunk) * (NINST*NBIN);
  #pragma unroll
  for (int k = 0; k < NINST*NBIN/K3T; ++k) {
    int idx = k*K3T + t;
    out[idx] = hc[(idx & 127)*HSTR + (idx >> 7)];
  }
}

// K4: per pair: 4 groups reduce 64 chunks each (coalesced), combine, then
// one wave does the 128-bin descending Lovasz scan.
__global__ __launch_bounds__(512) void k4_scan(
    const unsigned* __restrict__ hist, const float* __restrict__ der,
    float* __restrict__ instl)
{
  __shared__ unsigned s_c[4][NBIN], s_p[4][NBIN];
  int t = threadIdx.x;
  int pair = blockIdx.x;
  int b = pair >> 5, j = pair & 31;
  int grp = t >> 7, bin = t & 127;
  const unsigned* bp = hist + ((size_t)b*NCHUNK3*NINST + j)*NBIN + bin;
  unsigned c = 0, p = 0;
  #pragma unroll 8
  for (int ch = grp*64; ch < grp*64 + 64; ++ch) {
    unsigned v = bp[(size_t)ch * (NINST*NBIN)];
    c += v & 0xFFFFu; p += v >> 16;
  }
  s_c[grp][bin] = c; s_p[grp][bin] = p;
  __syncthreads();
  if (t < NBIN) {
    s_c[0][t] += s_c[1][t] + s_c[2][t] + s_c[3][t];
    s_p[0][t] += s_p[1][t] + s_p[2][t] + s_p[3][t];
  }
  __syncthreads();

  if (t < 64) {
    int lane = t;
    float G = der[5*128+pair];
    unsigned carryN = 0, carryP = 0;
    float Jprev = 0.f, L = 0.f;
    for (int c8 = 0; c8 < NBIN/64; ++c8) {
      int k = NBIN - 1 - c8*64 - lane;
      unsigned n = s_c[0][k], pp0 = s_p[0][k];
      for (int off = 1; off < 64; off <<= 1) {
        unsigned nn = __shfl_up(n, off);
        unsigned pq = __shfl_up(pp0, off);
        if (lane >= off) { n += nn; pp0 += pq; }
      }
      float fN = (float)(carryN + n);
      float fP = (float)(carryP + pp0);
      float uni = G + fN - fP;
      float J = 1.0f - (G - fP) / fmaxf(uni, 1e-9f);
      float Jp = __shfl_up(J, 1);
      if (lane == 0) Jp = Jprev;
      float v = (k + 0.5f) * (2.0f/NBIN);
      L += v * (J - Jp);
      carryN += __shfl(n, 63);
      carryP += __shfl(pp0, 63);
      Jprev  = __shfl(J, 63);
    }
    for (int o = 32; o; o >>= 1) L += __shfl_down(L, o);
    if (lane == 0) instl[pair] = L;
  }
}

// K5: final combine.
__global__ __launch_bounds__(256) void k5_final(
    const float* __restrict__ instl, const float* __restrict__ der,
    const float* __restrict__ seedbg, const float* __restrict__ sfg,
    float* __restrict__ out)
{
  __shared__ float red[256];
  int t = threadIdx.x;
  float acc = 0.f;
  for (int i = t; i < 1024; i += 256) acc += sfg[i];
  acc *= (1.0f/NPIX);
  if (t < 4) acc += seedbg[t] * (1.0f/NPIX);
  if (t < 128) acc += (instl[t] + 10.0f*der[4*128+t]) * (1.0f/NINST);
  red[t] = acc; __syncthreads();
  for (int s = 128; s; s >>= 1) { if (t < s) red[t] += red[t+s]; __syncthreads(); }
  if (t == 0) out[0] = red[0] * (1.0f/BB);
}

extern "C" void kernel_launch(void* const* d_in, const int* in_sizes, int n_in,
                              void* d_out, int out_size, void* d_ws, size_t ws_size,
                              hipStream_t stream)
{
  const float* pred = (const float*)d_in[0];
  const int* inst = (const int*)d_in[1];
  const int* lab  = (const int*)d_in[2];
  char* ws = (char*)d_ws;
  float* partA = (float*)(ws + OFF_PARTA);
  float* partSeed = (float*)(ws + OFF_PSEED);
  float* der = (float*)(ws + OFF_DER);
  float* seedbg = (float*)(ws + OFF_SEEDBG);
  float* instl = (float*)(ws + OFF_INSTL);
  float* sfg = (float*)(ws + OFF_SFG);
  uint2* rec = (uint2*)(ws + OFF_REC);
  unsigned* hist = (unsigned*)(ws + OFF_HIST);

  hipLaunchKernelGGL(k1_stats, dim3(256), dim3(256), 0, stream,
                     pred, inst, lab, partA, partSeed, rec);
  hipLaunchKernelGGL(k2_reduce, dim3(1), dim3(1024), 0, stream,
                     partA, partSeed, der, seedbg);
  hipLaunchKernelGGL(k3_hist, dim3(BB*NCHUNK3), dim3(K3T), 0, stream,
                     rec, der, hist, sfg);
  hipLaunchKernelGGL(k4_scan, dim3(128), dim3(512), 0, stream, hist, der, instl);
  hipLaunchKernelGGL(k5_final, dim3(1), dim3(256), 0, stream,
                     instl, der, seedbg, sfg, (float*)d_out);
}